// Round 13
// baseline (3234.205 us; speedup 1.0000x reference)
//
#include <hip/hip_runtime.h>
#include <cmath>

#define HID 150
#define FOURH 600
#define BATCH 64
#define TLEN 2048
#define NKS 5   // k-tiles of 32 for xproj MFMA
#define NQ 19   // 8-wide k-slots for recur (152 >= 150)

typedef _Float16 f16;
typedef __attribute__((ext_vector_type(2))) _Float16 half2_t;
typedef __attribute__((ext_vector_type(8))) _Float16 f16x8;
typedef __attribute__((ext_vector_type(4))) float f32x4;

#if defined(__has_builtin)
#if __has_builtin(__builtin_amdgcn_fdot2)
#define FDOT2(a, b, c) __builtin_amdgcn_fdot2((a), (b), (c), false)
#endif
#endif
#ifndef FDOT2
__device__ __forceinline__ float fdot2_fb(half2_t a, half2_t b, float c) {
    return c + (float)a.x * (float)b.x + (float)a.y * (float)b.y;
}
#define FDOT2(a, b, c) fdot2_fb((a), (b), (c))
#endif

__device__ __forceinline__ float tanhf_(float x) {
    return 1.0f - 2.0f / (__expf(2.0f * x) + 1.0f);
}

#define H2(x) __builtin_bit_cast(half2_t, (x))

// ======================= packing kernels =======================

// Wh -> recur layout: float4 slot q (0..18) of thread t = j*4+g holds
// k-pairs (q*8+2e, q*8+2e+1) of column g*150+j. half2 idx = (q*640+t)*4+e.
// A wave's load of slot q is lane-contiguous (1 KB/instruction).
#define WHR_PER_LAYER (NQ * 640 * 4)   // half2 count = 48640
__global__ void pack_whr(const float* __restrict__ Wh0, const float* __restrict__ Wh1,
                         half2_t* __restrict__ dst) {
    int idx = blockIdx.x * 256 + threadIdx.x;
    if (idx >= 2 * WHR_PER_LAYER) return;
    int layer = idx / WHR_PER_LAYER, r = idx - layer * WHR_PER_LAYER;
    int e = r & 3, qt = r >> 2;
    int t = qt % 640, q = qt / 640;
    int j = t >> 2, g = t & 3;
    int k0 = q * 8 + 2 * e;
    const float* Wh = layer ? Wh1 : Wh0;
    int col = g * HID + j;
    float a  = (j < HID && k0 < HID)     ? Wh[(size_t)k0 * FOURH + col]       : 0.f;
    float bb = (j < HID && k0 + 1 < HID) ? Wh[(size_t)(k0 + 1) * FOURH + col] : 0.f;
    half2_t h; h.x = (_Float16)a; h.y = (_Float16)bb;
    dst[idx] = h;
}

// Wx -> MFMA B-frags (layout verified on-device in r9):
// wxp[layer][f=ct*5+k5][lane][e] = Wx[k][n], n=ct*16+(lane&15), k=k5*32+(lane>>4)*8+e
#define WXP_PER_LAYER (38 * 5 * 64 * 8)
__global__ void pack_wxm(const float* __restrict__ Wx0, const float* __restrict__ Wx1,
                         f16* __restrict__ dst) {
    int idx = blockIdx.x * 256 + threadIdx.x;
    if (idx >= 2 * WXP_PER_LAYER) return;
    int layer = idx / WXP_PER_LAYER, r = idx - layer * WXP_PER_LAYER;
    int e = r & 7;
    int lane = (r >> 3) & 63;
    int f = r >> 9;                  // ct*5 + k5
    int k5 = f % 5, ct = f / 5;
    int n = ct * 16 + (lane & 15);
    int k = k5 * 32 + (lane >> 4) * 8 + e;
    const float* Wx = layer ? Wx1 : Wx0;
    float v = (n < FOURH && k < HID) ? Wx[(size_t)k * FOURH + n] : 0.f;
    dst[idx] = (f16)v;
}

// ======================= xproj via MFMA (r10, + permuted column write) =======================
// xp column layout is permuted to j*4+g so recur lanes read lane-contiguously.
__global__ __launch_bounds__(256) void xproj_mfma(
    int nA, const float* __restrict__ XA, const f16* __restrict__ wxA,
    const float* __restrict__ biasA, float* __restrict__ xdA, int tA,
    const float* __restrict__ XB, const f16* __restrict__ wxB,
    const float* __restrict__ biasB, float* __restrict__ xdB, int tB,
    int C)
{
    const int xg = C / 32;
    const int per = 64 * xg;
    int x = blockIdx.x;
    const int isB = (x >= nA * per) ? 1 : 0;
    if (isB) x -= nA * per;
    const float* X    = isB ? XB    : XA;
    const f16*   wx   = isB ? wxB   : wxA;
    const float* bias = isB ? biasB : biasA;
    float*       xd   = isB ? xdB   : xdA;
    const int    t0   = isB ? tB    : tA;

    const int b  = x / xg;
    const int i0 = (x - b * xg) * 32;
    const int tid = threadIdx.x;
    const int wv = tid >> 6;
    const int l  = tid & 63;

    __shared__ __align__(16) f16 Xs[32][168];

    const float* Xbase = X + ((size_t)(b * TLEN + t0 + i0)) * HID;
    #pragma unroll
    for (int it = 0; it < 20; ++it) {
        int idx = tid + it * 256;
        int r = idx / 160, k = idx - r * 160;
        Xs[r][k] = (f16)((k < HID) ? Xbase[(size_t)r * HID + k] : 0.f);
    }
    __syncthreads();

    f16x8 af[2][NKS];
    #pragma unroll
    for (int mt = 0; mt < 2; ++mt)
        #pragma unroll
        for (int k5 = 0; k5 < NKS; ++k5)
            af[mt][k5] = *(const f16x8*)&Xs[mt * 16 + (l & 15)][k5 * 32 + (l >> 4) * 8];

    const int n_lo = l & 15;
    const int r0 = (l >> 4) * 4;
    for (int ct = wv; ct < 38; ct += 4) {
        const f16* wb = wx + ((size_t)(ct * 5) * 64 + l) * 8;
        f32x4 acc0 = {0.f, 0.f, 0.f, 0.f};
        f32x4 acc1 = {0.f, 0.f, 0.f, 0.f};
        #pragma unroll
        for (int k5 = 0; k5 < NKS; ++k5) {
            f16x8 bf = *(const f16x8*)(wb + (size_t)k5 * 64 * 8);
            acc0 = __builtin_amdgcn_mfma_f32_16x16x32_f16(af[0][k5], bf, acc0, 0, 0, 0);
            acc1 = __builtin_amdgcn_mfma_f32_16x16x32_f16(af[1][k5], bf, acc1, 0, 0, 0);
        }
        const int n = ct * 16 + n_lo;
        if (n < FOURH) {
            float bv = bias[n];
            const int pcol = (n % HID) * 4 + n / HID;   // permuted column j*4+g
            float* o = xd + ((size_t)b * C + i0) * FOURH + pcol;
            #pragma unroll
            for (int r = 0; r < 4; ++r) {
                o[(size_t)(r0 + r) * FOURH]      = acc0[r] + bv;
                o[(size_t)(16 + r0 + r) * FOURH] = acc1[r] + bv;
            }
        }
    }
}

// ======================= recurrence: lane-local gates, 1 barrier/step =======================
// 4 fdot2 of one (h float4, w float4) pair = 8 k-values
#define D4(acc, hf, wf) \
  acc = FDOT2(H2((hf).x), H2((wf).x), acc); \
  acc = FDOT2(H2((hf).y), H2((wf).y), acc); \
  acc = FDOT2(H2((hf).z), H2((wf).z), acc); \
  acc = FDOT2(H2((hf).w), H2((wf).w), acc);

// One k-slot: coalesced weight float4 + broadcast h float4.
#define QS(q, acc) { \
  float4 wq = Wtt[(q) * 640]; \
  float4 hq = *(const float4*)(const void*)&h16[cur][(q) * 8]; \
  D4(acc, hq, wq) }

// Thread tid = j*4+g owns the FULL dot for (unit j, gate g): no partial
// reduction, no part_s. The 4 gates of unit j are adjacent lanes -> 3
// shfl_xor gathers them. h double-buffered -> ONE barrier per step.
// Weight stream: 19 lane-contiguous dwordx4/thread/step from L2 (the r5
// configuration, minus the overhead chain).
__global__ __launch_bounds__(640)
void lstm_recur6(const float* __restrict__ xpA, const float4* __restrict__ whrA,
                 float* __restrict__ stA, int t0A,
                 const float* __restrict__ xpB, const float4* __restrict__ whrB,
                 float* __restrict__ stB, int t0B,
                 float* __restrict__ out, int C)
{
    const int part = blockIdx.x >> 6;
    const int b = blockIdx.x & 63;
    const int tid = threadIdx.x;
    const int j = tid >> 2;      // unit 0..159 (>=150 pad)
    const int g = tid & 3;       // gate

    const float*  xp    = part ? xpB  : xpA;
    const float4* Wt    = part ? whrB : whrA;
    float*        state = part ? stB  : stA;
    const int     t0    = part ? t0B  : t0A;

    __shared__ __align__(16) _Float16 h16[2][160];

    const float4* Wtt = Wt + tid;

    // activation constants: sigmoid for g in {0,1,3}, tanh for g==2
    const float sS = (g == 2) ? 2.f : 1.f;
    const float sM = (g == 2) ? 2.f : 1.f;
    const float sO = (g == 2) ? -1.f : 0.f;

    // init h (both halves' tails stay consistent via full writes each step)
    if (tid < 160) {
        float hv = 0.f;
        if (t0 != 0 && tid < HID) hv = state[b * 300 + HID + tid];
        h16[0][tid] = (_Float16)hv;
    }
    float cst = 0.f;
    if (g == 0 && t0 != 0 && j < HID) cst = state[b * 300 + j];
    __syncthreads();

    const float* xpb = xp + (size_t)b * C * FOURH;
    float* outb = out + ((size_t)b * TLEN + t0) * HID;

    float xn = (tid < FOURH) ? xpb[tid] : 0.f;

    int cur = 0;
    for (int i = 0; i < C; ++i) {
        float xc = xn;
        if (tid < FOURH && i + 1 < C) xn = xpb[(size_t)(i + 1) * FOURH + tid];

        float a0 = 0.f, a1 = 0.f, a2 = 0.f, a3 = 0.f;
        QS(0, a0)  QS(1, a1)  QS(2, a2)  QS(3, a3)
        QS(4, a0)  QS(5, a1)  QS(6, a2)  QS(7, a3)
        QS(8, a0)  QS(9, a1)  QS(10, a2) QS(11, a3)
        QS(12, a0) QS(13, a1) QS(14, a2) QS(15, a3)
        QS(16, a0) QS(17, a1) QS(18, a2)
        float z = xc + (a0 + a1) + (a2 + a3);

        // branchless activation
        float act = sM / (1.f + __expf(-sS * z)) + sO;

        // gather the quad's 4 gates into lane g==0
        float x1 = __shfl_xor(act, 1);
        float x2 = __shfl_xor(act, 2);
        float x3 = __shfl_xor(act, 3);

        if (g == 0) {
            // lane0: act=i, x1=f, x2=g, x3=o
            cst = x1 * cst + act * x2;
            float hn = x3 * tanhf_(cst);
            h16[cur ^ 1][j] = (_Float16)hn;
            if (j < HID) outb[(size_t)i * HID + j] = hn;
        }
        __syncthreads();
        cur ^= 1;
    }

    if (g == 0 && j < HID) {
        state[b * 300 + j] = cst;
        state[b * 300 + HID + j] = (float)h16[cur][j];
    }
}

extern "C" void kernel_launch(void* const* d_in, const int* in_sizes, int n_in,
                              void* d_out, int out_size, void* d_ws, size_t ws_size,
                              hipStream_t stream) {
    const float* xs  = (const float*)d_in[0];
    const float* Wx0 = (const float*)d_in[1];
    const float* Wh0 = (const float*)d_in[2];
    const float* b0  = (const float*)d_in[3];
    const float* Wx1 = (const float*)d_in[4];
    const float* Wh1 = (const float*)d_in[5];
    const float* b1  = (const float*)d_in[6];
    float* out = (float*)d_out;

    int C = 256;
    {
        size_t need = 2ull * BATCH * C * FOURH * 4 + 2ull * WHR_PER_LAYER * 4
                    + 2ull * WXP_PER_LAYER * 2 + 2ull * BATCH * 300 * 4;
        if (need > ws_size) C = 128;
    }
    const size_t xpsz = (size_t)BATCH * C * FOURH * 4;
    char* p = (char*)d_ws;
    float* xp0 = (float*)p;      p += xpsz;
    float* xp1 = (float*)p;      p += xpsz;
    half2_t* whr = (half2_t*)p;  p += 2ull * WHR_PER_LAYER * 4;
    f16* wxp = (f16*)p;          p += 2ull * WXP_PER_LAYER * 2;
    float* st0 = (float*)p;      p += (size_t)BATCH * 300 * 4;
    float* st1 = (float*)p;
    const float4* whr0 = (const float4*)whr;
    const float4* whr1 = (const float4*)(whr + WHR_PER_LAYER);
    const f16* wxp0 = wxp;
    const f16* wxp1 = wxp + WXP_PER_LAYER;

    pack_whr<<<dim3((2 * WHR_PER_LAYER + 255) / 256), dim3(256), 0, stream>>>(Wh0, Wh1, whr);
    pack_wxm<<<dim3((2 * WXP_PER_LAYER + 255) / 256), dim3(256), 0, stream>>>(Wx0, Wx1, wxp);

    const int nchunk = TLEN / C;
    const int xg = C / 32;

    // Slot s: xproj(L0 chunk s + L1 chunk s-1) then recur(L0 s || L1 s-1).
    for (int s = 0; s <= nchunk; ++s) {
        const int hasA = (s < nchunk) ? 1 : 0;
        const int hasB = (s >= 1) ? 1 : 0;
        xproj_mfma<<<dim3((hasA + hasB) * 64 * xg), dim3(256), 0, stream>>>(
            hasA, xs, wxp0, b0, xp0, s * C,
            out, wxp1, b1, xp1, (s - 1) * C, C);
        if (hasA && hasB)
            lstm_recur6<<<dim3(128), dim3(640), 0, stream>>>(
                xp0, whr0, st0, s * C, xp1, whr1, st1, (s - 1) * C, out, C);
        else if (hasA)
            lstm_recur6<<<dim3(64), dim3(640), 0, stream>>>(
                xp0, whr0, st0, s * C, xp0, whr0, st0, 0, out, C);
        else
            lstm_recur6<<<dim3(64), dim3(640), 0, stream>>>(
                xp1, whr1, st1, (s - 1) * C, xp1, whr1, st1, 0, out, C);
    }
}